// Round 8
// baseline (194.924 us; speedup 1.0000x reference)
//
#include <hip/hip_runtime.h>
#include <math.h>

// Problem constants (from reference)
#define NROWS 84
#define SLEN  131072
#define BLOCKS_PER_ROW 8
#define THREADS 256
#define ROUNDS 16
// Segment per block = SLEN/8 = 16384 floats = 4096 float4
//   = ROUNDS(16) x THREADS(256) float4 per tensor.  (R7 had rounds x threads
//   = 2x the segment -> OOB page fault. Fixed here.)
// R5/R6: nt loads -> ~4.4 TB/s read, invariant across loop/burst schedules
// at 8 outstanding loads/wave. R8 single variable: pipeline depth 4 -> 6
// (12 outstanding dwordx4 = 12 KB/wave), 16 rounds so steady state exists.

typedef float f32x4 __attribute__((ext_vector_type(4)));

__device__ __forceinline__ float sigw(float x, float b, float bias) {
    return __frcp_rn(1.0f + __expf(-b * (bias + x)));
}

__global__ __launch_bounds__(THREADS) void rowdot_kernel(
    const float* __restrict__ ST0, const float* __restrict__ W0,
    const float* __restrict__ ST1, const float* __restrict__ W1,
    const float* __restrict__ BEV, const float* __restrict__ BEV_p,
    const float* __restrict__ B, float* __restrict__ tmp /* 1344 floats */)
{
    const int bid = blockIdx.x;
    const int tensor = (bid >= NROWS * BLOCKS_PER_ROW) ? 1 : 0;
    const int local  = bid - tensor * NROWS * BLOCKS_PER_ROW;
    const int row = local / BLOCKS_PER_ROW;
    const int seg = local % BLOCKS_PER_ROW;

    const float* __restrict__ STp = tensor ? ST1 : ST0;
    const float* __restrict__ Wp  = tensor ? W1  : W0;

    const float bias = fmaxf(BEV_p[0], 0.0f) * BEV[0];
    const float b    = B[0];

    const size_t base = (size_t)row * SLEN + (size_t)seg * (SLEN / BLOCKS_PER_ROW);
    const int t = threadIdx.x;
    const f32x4* sp = (const f32x4*)(STp + base) + t;
    const f32x4* wp = (const f32x4*)(Wp  + base) + t;

    f32x4 s0, s1, s2, s3, s4, s5, w0, w1, w2, w3, w4, w5;
    float a0 = 0.f, a1 = 0.f, a2 = 0.f, a3 = 0.f;

    // Non-temporal streaming loads (evict-first): the R5 win.
#define ISSUE(i, ss, ww)                                                   \
    asm volatile("global_load_dwordx4 %0, %1, off nt"                      \
                 : "=v"(ss) : "v"(sp + (i) * THREADS));                    \
    asm volatile("global_load_dwordx4 %0, %1, off nt"                      \
                 : "=v"(ww) : "v"(wp + (i) * THREADS));

#define WAITN(n, ss, ww)                                                   \
    asm volatile("s_waitcnt vmcnt(" #n ")" : "+v"(ss), "+v"(ww));

#define COMPUTE(ss, ww)                                                    \
    a0 += (ww).x * sigw((ss).x, b, bias);                                  \
    a1 += (ww).y * sigw((ss).y, b, bias);                                  \
    a2 += (ww).z * sigw((ss).z, b, bias);                                  \
    a3 += (ww).w * sigw((ss).w, b, bias);

    // Prologue: rounds 0..5 -> 12 loads in flight.
    ISSUE(0, s0, w0) ISSUE(1, s1, w1) ISSUE(2, s2, w2)
    ISSUE(3, s3, w3) ISSUE(4, s4, w4) ISSUE(5, s5, w5)

    // Steady state (rounds 6..15): wait oldest pair, compute, refill slot.
    WAITN(10, s0, w0) COMPUTE(s0, w0) ISSUE( 6, s0, w0)
    WAITN(10, s1, w1) COMPUTE(s1, w1) ISSUE( 7, s1, w1)
    WAITN(10, s2, w2) COMPUTE(s2, w2) ISSUE( 8, s2, w2)
    WAITN(10, s3, w3) COMPUTE(s3, w3) ISSUE( 9, s3, w3)
    WAITN(10, s4, w4) COMPUTE(s4, w4) ISSUE(10, s4, w4)
    WAITN(10, s5, w5) COMPUTE(s5, w5) ISSUE(11, s5, w5)
    WAITN(10, s0, w0) COMPUTE(s0, w0) ISSUE(12, s0, w0)
    WAITN(10, s1, w1) COMPUTE(s1, w1) ISSUE(13, s1, w1)
    WAITN(10, s2, w2) COMPUTE(s2, w2) ISSUE(14, s2, w2)
    WAITN(10, s3, w3) COMPUTE(s3, w3) ISSUE(15, s3, w3)

    // Drain (slots hold rounds 10..15 -> order s4,s5,s0,s1,s2,s3).
    WAITN(10, s4, w4) COMPUTE(s4, w4)
    WAITN( 8, s5, w5) COMPUTE(s5, w5)
    WAITN( 6, s0, w0) COMPUTE(s0, w0)
    WAITN( 4, s1, w1) COMPUTE(s1, w1)
    WAITN( 2, s2, w2) COMPUTE(s2, w2)
    WAITN( 0, s3, w3) COMPUTE(s3, w3)

#undef ISSUE
#undef WAITN
#undef COMPUTE

    float acc = (a0 + a1) + (a2 + a3);

    // wave-64 reduction
#pragma unroll
    for (int off = 32; off > 0; off >>= 1)
        acc += __shfl_down(acc, off, 64);

    __shared__ float sdata[THREADS / 64];
    if ((t & 63) == 0) sdata[t >> 6] = acc;
    __syncthreads();

    if (t == 0) {
        float ssum = 0.0f;
#pragma unroll
        for (int wv = 0; wv < THREADS / 64; ++wv) ssum += sdata[wv];
        tmp[bid] = ssum;   // private slot — no atomic, no init needed
    }
}

__global__ void finalize_kernel(
    const float* __restrict__ tmp,   /* 1344 block partials */
    const float* __restrict__ p0, const float* __restrict__ p1,
    const float* __restrict__ p2, const float* __restrict__ p3,
    const float* __restrict__ p4, float* __restrict__ out)
{
    __shared__ float rowsum[2 * NROWS];
    const int t = threadIdx.x;

    // tmp[bid], bid = (tensor*84 + row)*8 + seg  ->  thread t<168 sums
    // the 8 contiguous partials of logical row t.
    if (t < 2 * NROWS) {
        const float* p = tmp + t * BLOCKS_PER_ROW;
        float s = 0.0f;
#pragma unroll
        for (int i = 0; i < BLOCKS_PER_ROW; ++i) s += p[i];
        rowsum[t] = s;
    }
    __syncthreads();

    if (t == 0) {
        const float* logits[5] = {p0, p1, p2, p3, p4};
        float total = 0.0f;
        for (int set = 0; set < 5; ++set) {
            const float* lg = logits[set];
            float m = fmaxf(fmaxf(lg[0], lg[1]), fmaxf(lg[2], lg[3]));
            float e[4], sum = 0.0f;
            for (int i = 0; i < 4; ++i) { e[i] = expf(lg[i] - m); sum += e[i]; }
            float p[4];
            for (int i = 0; i < 4; ++i) p[i] = e[i] / sum;

            const float* tv = (set == 0) ? rowsum : rowsum + NROWS;

            float dot = 0.0f;
            int idx = 0;
            for (int i = 0; i < 4; ++i) {
                dot += p[i] * tv[idx++];
                for (int j = 0; j < 4; ++j) {
                    float pij = p[i] * p[j];
                    dot += pij * tv[idx++];
                    for (int k = 0; k < 4; ++k)
                        dot += pij * p[k] * tv[idx++];
                }
            }
            total += dot;
        }
        out[0] = total * 0.2f;  // mean of 5 vals
    }
}

extern "C" void kernel_launch(void* const* d_in, const int* in_sizes, int n_in,
                              void* d_out, int out_size, void* d_ws, size_t ws_size,
                              hipStream_t stream) {
    const float* BEV   = (const float*)d_in[0];
    const float* ST0   = (const float*)d_in[1];
    const float* W0    = (const float*)d_in[2];
    const float* ST1   = (const float*)d_in[3];
    const float* W1    = (const float*)d_in[4];
    const float* p0    = (const float*)d_in[5];
    const float* p1    = (const float*)d_in[6];
    const float* p2    = (const float*)d_in[7];
    const float* p3    = (const float*)d_in[8];
    const float* p4    = (const float*)d_in[9];
    const float* BEV_p = (const float*)d_in[10];
    const float* B     = (const float*)d_in[11];

    float* tmp = (float*)d_ws;                 // 1344 block partials
    float* out = (float*)d_out;

    const int grid = 2 * NROWS * BLOCKS_PER_ROW;  // 1344 blocks
    rowdot_kernel<<<grid, THREADS, 0, stream>>>(ST0, W0, ST1, W1, BEV, BEV_p, B, tmp);
    finalize_kernel<<<1, 256, 0, stream>>>(tmp, p0, p1, p2, p3, p4, out);
}